// Round 22
// baseline (105.539 us; speedup 1.0000x reference)
//
#include <hip/hip_runtime.h>
#include <hip/hip_bf16.h>
#include <math.h>

typedef unsigned short u16;
typedef unsigned int u32;
typedef __attribute__((ext_vector_type(4))) float f32x4;
typedef __attribute__((ext_vector_type(8))) short bf16x8;

#define B_ 2
#define S_ 2048
#define D_ 1024
#define H_ 16
#define DK_ 64

// v_exp_f32: computes 2^x. Name avoids glibc __exp2f macro collision.
__device__ __forceinline__ float exp2_fast(float x) {
    return __builtin_amdgcn_exp2f(x);
}

__device__ __forceinline__ u16 f2bf(float x) {
    union { __hip_bfloat16 h; u16 u; } v;
    v.h = __float2bfloat16(x);
    return v.u;
}

// pack two f32 -> one u32 of 2 bf16 (RNE), single instruction
__device__ __forceinline__ u32 cvt_pk_bf16(float a, float b) {
    u32 r;
    asm("v_cvt_pk_bf16_f32 %0, %1, %2" : "=v"(r) : "v"(a), "v"(b));
    return r;
}

__device__ __forceinline__ void gload_lds16(const u16* g, u16* l) {
    __builtin_amdgcn_global_load_lds(
        (const __attribute__((address_space(1))) unsigned int*)g,
        (__attribute__((address_space(3))) unsigned int*)l, 16, 0, 0);
}

// ---------------------------------------------------------------------------
// Fused prep kernel: one launch, flat grid of 3088 blocks. (Passing R20/R21.)
// ---------------------------------------------------------------------------
__device__ __forceinline__ void transpose_tile_body(
    const float* __restrict__ W, u16* __restrict__ WT, int N,
    int k0, int n0, int t, float (*tile)[65])
{
    const int r = t >> 4, c4 = (t & 15) * 4;
#pragma unroll
    for (int p = 0; p < 4; ++p) {
        float4 v = *(const float4*)&W[(size_t)(k0 + r + p * 16) * N + n0 + c4];
        tile[r + p * 16][c4 + 0] = v.x;
        tile[r + p * 16][c4 + 1] = v.y;
        tile[r + p * 16][c4 + 2] = v.z;
        tile[r + p * 16][c4 + 3] = v.w;
    }
    __syncthreads();
    const int nl = t >> 2, kc = (t & 3) * 16;
    u16 buf[16];
#pragma unroll
    for (int j = 0; j < 16; ++j) buf[j] = f2bf(tile[kc + j][nl]);
    const size_t idx = (size_t)(n0 + nl) * 1024 + k0 + kc;
    u32 px[8];
#pragma unroll
    for (int j = 0; j < 8; ++j) px[j] = (u32)buf[2 * j] | ((u32)buf[2 * j + 1] << 16);
    *(uint4*)&WT[idx]     = make_uint4(px[0], px[1], px[2], px[3]);
    *(uint4*)&WT[idx + 8] = make_uint4(px[4], px[5], px[6], px[7]);
}

__global__ __launch_bounds__(256) void prep_all(
    const float* __restrict__ X, const float* __restrict__ Wqkv,
    const float* __restrict__ Wo, const int* __restrict__ pos,
    u16* __restrict__ Xb, u16* __restrict__ WqT, u16* __restrict__ WoT,
    float2* __restrict__ tab)
{
    __shared__ float tile[64][65];
    const int bid = blockIdx.x;
    const int t = threadIdx.x;

    if (bid < 2048) {
        // ---- cast X fp32 -> bf16 ----
        const int i = (bid * 256 + t) * 8;
        float4 a = *(const float4*)(X + i);
        float4 b = *(const float4*)(X + i + 4);
        u32 p0 = cvt_pk_bf16(a.x, a.y);
        u32 p1 = cvt_pk_bf16(a.z, a.w);
        u32 p2 = cvt_pk_bf16(b.x, b.y);
        u32 p3 = cvt_pk_bf16(b.z, b.w);
        *(uint4*)(Xb + i) = make_uint4(p0, p1, p2, p3);
    } else if (bid < 2816) {
        const int tl = bid - 2048;            // 0..767 = 16 k-tiles x 48 n-tiles
        transpose_tile_body(Wqkv, WqT, 3072, (tl & 15) * 64, (tl >> 4) * 64, t, tile);
    } else if (bid < 3072) {
        const int tl = bid - 2816;            // 0..255 = 16 x 16
        transpose_tile_body(Wo, WoT, 1024, (tl & 15) * 64, (tl >> 4) * 64, t, tile);
    } else {
        // ---- RoPE table: 65536 entries over 16 blocks ----
        const int base = (bid - 3072) * 256 + t;
#pragma unroll
        for (int k = 0; k < 16; ++k) {
            const int i = base + k * 4096;
            const int s = i >> 5, j = i & 31;
            const float freq = __powf(10000.f, -(float)(2 * j) * (1.f / 64.f));
            const float ang = (float)pos[s] * freq;
            float sn, cs;
            sincosf(ang, &sn, &cs);
            tab[i] = make_float2(cs, sn);
        }
    }
}

// ---------------------------------------------------------------------------
// Kernel: QKV GEMM + RoPE epilogue. R22: 128x64 tiles (same transformation
// validated on gemm_out in R21): grid (32,48) = 1536 blocks, LDS 48 KB ->
// 3 blocks/CU (was 2). BK=64, 8 waves (4M x 2N, wave n-range 32),
// 3 VMEM/K-step, counted vmcnt(3).
// Q scaled by 0.125*log2(e). Q,K roped -> [B,H,S,DK]; V -> [B,H,DK,S] (V^T).
// Tile is 64 n wide = exactly one head; region = n0>>10 (by: 0-15 Q,
// 16-31 K, 32-47 V).
// ---------------------------------------------------------------------------
__global__ __launch_bounds__(512, 4) void gemm_qkv_rope(
    const u16* __restrict__ A, const u16* __restrict__ BT,
    const float2* __restrict__ tab,
    u16* __restrict__ qo, u16* __restrict__ ko, u16* __restrict__ vto)
{
    __shared__ u16 lA[2 * 128 * 64];
    __shared__ u16 lB[2 * 64 * 64];
    const int tid = threadIdx.x, l = tid & 63, w = tid >> 6;
    const int m0 = blockIdx.x * 128, n0 = blockIdx.y * 64;
    const int K = 1024;

    const int wr = w >> 1, wc = w & 1, lr = l & 15, lg = l >> 4;
    const int srow = tid >> 3;                     // 0..63
    const int cg   = (tid & 7) ^ (srow & 7);
    const u16* gA = A + (size_t)(m0 + srow) * K + cg * 8;
    const u16* gB = BT + (size_t)(n0 + srow) * K + cg * 8;
    const int dst0 = tid * 8;

    f32x4 acc[2][2] = {};

#define GSTAGE2(k0, offA, offB)                                      \
    do {                                                             \
        gload_lds16(gA + (k0),          lA + (offA) + dst0);         \
        gload_lds16(gA + (k0) + 64 * K, lA + (offA) + 4096 + dst0);  \
        gload_lds16(gB + (k0),          lB + (offB) + dst0);         \
    } while (0)

    GSTAGE2(0, 0, 0);

    const int NT = K >> 6;   // 16 K-tiles
    for (int t = 0; t < NT; ++t) {
        const int coffA = (t & 1) * 8192;
        const int coffB = (t & 1) * 4096;
        if (t + 1 < NT) {
            GSTAGE2((t + 1) * 64, coffA ^ 8192, coffB ^ 4096);
            asm volatile("s_waitcnt vmcnt(3)" ::: "memory");  // cur landed
        } else {
            asm volatile("s_waitcnt vmcnt(0)" ::: "memory");
        }
        __builtin_amdgcn_s_barrier();
        __builtin_amdgcn_sched_barrier(0);

        bf16x8 a[2][2], b[2][2];
#pragma unroll
        for (int i = 0; i < 2; ++i) {
            const int row = wr * 32 + i * 16 + lr;
#pragma unroll
            for (int s = 0; s < 2; ++s)
                a[i][s] = *(const bf16x8*)(lA + coffA + row * 64 + (((s * 4 + lg) ^ (row & 7)) * 8));
        }
#pragma unroll
        for (int j = 0; j < 2; ++j) {
            const int row = wc * 32 + j * 16 + lr;
#pragma unroll
            for (int s = 0; s < 2; ++s)
                b[j][s] = *(const bf16x8*)(lB + coffB + row * 64 + (((s * 4 + lg) ^ (row & 7)) * 8));
        }
#pragma unroll
        for (int s = 0; s < 2; ++s)
#pragma unroll
            for (int i = 0; i < 2; ++i)
#pragma unroll
                for (int j = 0; j < 2; ++j)
                    acc[i][j] = __builtin_amdgcn_mfma_f32_16x16x32_bf16(a[i][s], b[j][s], acc[i][j], 0, 0, 0);

        asm volatile("s_waitcnt lgkmcnt(0)" ::: "memory");
        __builtin_amdgcn_s_barrier();
        __builtin_amdgcn_sched_barrier(0);
    }
#undef GSTAGE2

    const int region = n0 >> 10;  // 0=Q,1=K,2=V
    const int h = (n0 >> 6) & 15; // tile is 64-wide: exactly one head

    if (region < 2) {
        u16* dst = (region == 0) ? qo : ko;
        const float qscale = (region == 0) ? (0.125f * 1.44269504088896f) : 1.0f;
#pragma unroll
        for (int j = 0; j < 2; ++j) {
            const int c = wc * 32 + j * 16 + lr;   // col within head (0..63)
#pragma unroll
            for (int i = 0; i < 2; ++i) {
#pragma unroll
                for (int r = 0; r < 4; ++r) {
                    const int m = m0 + wr * 32 + i * 16 + lg * 4 + r;
                    const int bb = m >> 11, s = m & (S_ - 1);
                    const float2 cs = tab[s * 32 + (c >> 1)];
                    const float v = acc[i][j][r];
                    const float vp = __shfl_xor(v, 1);
                    float outv = ((lr & 1) == 0) ? (v * cs.x - vp * cs.y)
                                                 : (v * cs.x + vp * cs.y);
                    outv *= qscale;
                    dst[(((size_t)bb * H_ + h) * S_ + s) * DK_ + c] = f2bf(outv);
                }
            }
        }
    } else {
#pragma unroll
        for (int j = 0; j < 2; ++j) {
            const int c = wc * 32 + j * 16 + lr;
#pragma unroll
            for (int i = 0; i < 2; ++i) {
                // 4 r-values -> 4 consecutive s (same bb; base 4-aligned,
                // never crosses the 2048 boundary). Pack into one uint2.
                const int m = m0 + wr * 32 + i * 16 + lg * 4;
                const int bb = m >> 11, s = m & (S_ - 1);
                const u32 lo = cvt_pk_bf16(acc[i][j][0], acc[i][j][1]);
                const u32 hi = cvt_pk_bf16(acc[i][j][2], acc[i][j][3]);
                *(uint2*)&vto[(((size_t)bb * H_ + h) * DK_ + c) * S_ + s] =
                    make_uint2(lo, hi);
            }
        }
    }
}

// ---------------------------------------------------------------------------
// Flash attention (R16, passing): KVBLK=128, double-buffered LDS,
// XCD-local grid, swapped-operand MFMA, no-max exp2 softmax + MFMA
// ones-trick row-sum. UNCHANGED from the R16/R19/R20/R21 passing build.
// ---------------------------------------------------------------------------
__global__ __launch_bounds__(256) void attn_mfma(
    const u16* __restrict__ Qg, const u16* __restrict__ Kg,
    const u16* __restrict__ VTg, u16* __restrict__ Og)
{
    __shared__ u16 sK[2][128 * 64];    // [key][d]
    __shared__ u16 sV[2][64 * 128];    // [d][key]
    const int t = threadIdx.x, l = t & 63, w = t >> 6;
    const int lr = l & 15, lg = l >> 4;
    const int bh = blockIdx.x;          // id%8 == bh%8 -> XCD-local K/V
    const int qt = 31 - blockIdx.y;     // LPT: longest stripes first
    const int q0 = qt * 64 + w * 16;
    const int dt = qt >> 1;             // diagonal 128-key tile
    const int NT = dt + 1;
    const int qloc = (qt & 1) * 64 + w * 16 + lr;  // causal bound in dt

    const u16* Kbh = Kg + (size_t)bh * S_ * DK_;
    const u16* Vbh = VTg + (size_t)bh * DK_ * S_;

    const u16* Qp = Qg + ((size_t)bh * S_ + q0) * DK_;
    bf16x8 qa[2];
    qa[0] = *(const bf16x8*)(Qp + lr * DK_ + lg * 8);
    qa[1] = *(const bf16x8*)(Qp + lr * DK_ + 32 + lg * 8);

    // all-ones bf16 fragment for the MFMA row-sum (bf16 1.0 = 0x3F80)
    union { u32 wd[4]; bf16x8 v; } ones;
#pragma unroll
    for (int i = 0; i < 4; ++i) ones.wd[i] = 0x3F803F80u;

    // staging: K wave rows w*32..+31 (4 issues x 8 rows, 128B rows);
    //          V wave d-rows w*16..+15 (4 issues x 4 rows, 256B rows)
    const int kcg = (l & 7) ^ (l >> 3);   // krow&7 == l>>3 (w*32, i*8 = 0 mod 8)

#define STAGE(kt, b)                                                          \
    do {                                                                      \
        _Pragma("unroll")                                                     \
        for (int i = 0; i < 4; ++i) {                                         \
            const int kr = w * 32 + i * 8 + (l >> 3);                         \
            gload_lds16(Kbh + ((size_t)(kt) * 128 + kr) * DK_ + kcg * 8,      \
                        &sK[b][(w * 32 + i * 8) * 64]);                       \
        }                                                                     \
        _Pragma("unroll")                                                     \
        for (int i = 0; i < 4; ++i) {                                         \
            const int vr = w * 16 + i * 4 + (l >> 4);                         \
            const int vc = (l & 15) ^ ((i * 4 + (l >> 4)) & 15);              \
            gload_lds16(Vbh + (size_t)vr * S_ + (kt) * 128 + vc * 8,          \
                        &sV[b][(w * 16 + i * 4) * 128]);                      \
        }                                                                     \
    } while (0)

    f32x4 o[4] = {};                    // O^T: o[jf][r] = O[d][q=lr]
    f32x4 o5 = {};                      // row-sum accumulator (all rows equal)

    const int s0 = lr + 32 * (lg & 1);  // P-redistribution source lanes
    const int s1 = s0 + 16;
    const bool hi2 = (lg >= 2);

    STAGE(0, 0);
    asm volatile("s_waitcnt vmcnt(0)" ::: "memory");
    __syncthreads();

    for (int kt = 0; kt < NT; ++kt) {
        const int cur = kt & 1;
        if (kt + 1 < NT) STAGE(kt + 1, cur ^ 1);

        // ---- QK^T swapped: s4[kf] = K_frag x Q_frag -> [key][q], kf 0..7 ----
        f32x4 s4[8] = {};
        __builtin_amdgcn_s_setprio(1);
#pragma unroll
        for (int kf = 0; kf < 8; ++kf) {
            const int row = kf * 16 + lr;
#pragma unroll
            for (int ks = 0; ks < 2; ++ks) {
                bf16x8 kb = *(const bf16x8*)(&sK[cur][row * 64 + (((ks * 4 + lg) ^ (row & 7)) * 8)]);
                s4[kf] = __builtin_amdgcn_mfma_f32_16x16x32_bf16(kb, qa[ks], s4[kf], 0, 0, 0);
            }
        }
        __builtin_amdgcn_s_setprio(0);
        if (kt == dt) {
#pragma unroll
            for (int kf = 0; kf < 8; ++kf)
#pragma unroll
                for (int r = 0; r < 4; ++r)
                    if (kf * 16 + lg * 4 + r > qloc) s4[kf][r] = -3.0e38f;
        }

        // ---- no-max softmax: P = exp2(S) (masked -> 0); no reductions ----
#pragma unroll
        for (int kf = 0; kf < 8; ++kf)
#pragma unroll
            for (int r = 0; r < 4; ++r)
                s4[kf][r] = exp2_fast(s4[kf][r]);

        // ---- P redistribution (regs only): pk[8][2] -> pa[4] ----
        u32 pk[8][2];
#pragma unroll
        for (int kf = 0; kf < 8; ++kf) {
            pk[kf][0] = cvt_pk_bf16(s4[kf][0], s4[kf][1]);
            pk[kf][1] = cvt_pk_bf16(s4[kf][2], s4[kf][3]);
        }
        union { u32 wd[4]; bf16x8 v; } pa[4];
#pragma unroll
        for (int ks = 0; ks < 4; ++ks) {
            const u32 lo0 = pk[2 * ks][0],     lo1 = pk[2 * ks][1];
            const u32 hi0 = pk[2 * ks + 1][0], hi1 = pk[2 * ks + 1][1];
            const u32 a0 = __shfl(lo0, s0), b0 = __shfl(hi0, s0);
            const u32 a1 = __shfl(lo1, s0), b1 = __shfl(hi1, s0);
            const u32 a2 = __shfl(lo0, s1), b2 = __shfl(hi0, s1);
            const u32 a3 = __shfl(lo1, s1), b3 = __shfl(hi1, s1);
            pa[ks].wd[0] = hi2 ? b0 : a0;
            pa[ks].wd[1] = hi2 ? b1 : a1;
            pa[ks].wd[2] = hi2 ? b2 : a2;
            pa[ks].wd[3] = hi2 ? b3 : a3;
        }

        // ---- PV swapped + MFMA row-sum: o += V x P ; o5 += ones x P ----
        __builtin_amdgcn_s_setprio(1);
#pragma unroll
        for (int ks = 0; ks < 4; ++ks) {
#pragma unroll
            for (int jf = 0; jf < 4; ++jf) {
                const int row = jf * 16 + lr;
                bf16x8 vb = *(const bf16x8*)(&sV[cur][row * 128 + (((ks * 4 + lg) ^ (row & 15)) * 8)]);
                o[jf] = __builtin_amdgcn_mfma_f32_16x16x32_bf16(vb, pa[ks].v, o[jf], 0, 0, 0);
            }
            o5 = __builtin_amdgcn_mfma_f32_16x16x32_bf16(ones.v, pa[ks].v, o5, 0, 0, 0);
        }
        __builtin_amdgcn_s_setprio(0);

        asm volatile("s_waitcnt vmcnt(0)" ::: "memory");
        __syncthreads();
    }
#undef STAGE

    // ---- epilogue: normalize by li = o5[0], write O^T to [B,S,D] bf16 ----
    const float inv = 1.f / o5[0];
    const int b = bh >> 4, h = bh & 15;
    const int srow = q0 + lr;
    u16* orow = Og + ((size_t)b * S_ + srow) * D_ + h * DK_;
#pragma unroll
    for (int jf = 0; jf < 4; ++jf) {
#pragma unroll
        for (int p = 0; p < 2; ++p) {
            const u32 wv = cvt_pk_bf16(o[jf][2 * p] * inv, o[jf][2 * p + 1] * inv);
            *(u32*)(orow + jf * 16 + lg * 4 + 2 * p) = wv;
        }
    }
}

// ---------------------------------------------------------------------------
// Kernel: out = attn[4096][1024] @ Wo, fp32 out. 128x64 tiles, grid (32,16)
// = 512 blocks = 2 blocks/CU. (Passing R21 build, unchanged.)
// ---------------------------------------------------------------------------
__global__ __launch_bounds__(512, 4) void gemm_out(
    const u16* __restrict__ A, const u16* __restrict__ BT, float* __restrict__ C)
{
    __shared__ u16 lA[2 * 128 * 64];
    __shared__ u16 lB[2 * 64 * 64];
    const int tid = threadIdx.x, l = tid & 63, w = tid >> 6;
    const int m0 = blockIdx.x * 128, n0 = blockIdx.y * 64;
    const int K = 1024;

    const int wr = w >> 1, wc = w & 1, lr = l & 15, lg = l >> 4;
    const int srow = tid >> 3;                     // 0..63
    const int cg   = (tid & 7) ^ (srow & 7);
    const u16* gA = A + (size_t)(m0 + srow) * K + cg * 8;
    const u16* gB = BT + (size_t)(n0 + srow) * K + cg * 8;
    const int dst0 = tid * 8;

    f32x4 acc[2][2] = {};

#define GSTAGE2(k0, offA, offB)                                      \
    do {                                                             \
        gload_lds16(gA + (k0),          lA + (offA) + dst0);         \
        gload_lds16(gA + (k0) + 64 * K, lA + (offA) + 4096 + dst0);  \
        gload_lds16(gB + (k0),          lB + (offB) + dst0);         \
    } while (0)

    GSTAGE2(0, 0, 0);

    const int NT = K >> 6;   // 16 K-tiles
    for (int t = 0; t < NT; ++t) {
        const int coffA = (t & 1) * 8192;
        const int coffB = (t & 1) * 4096;
        if (t + 1 < NT) {
            GSTAGE2((t + 1) * 64, coffA ^ 8192, coffB ^ 4096);
            asm volatile("s_waitcnt vmcnt(3)" ::: "memory");  // cur landed
        } else {
            asm volatile("s_waitcnt vmcnt(0)" ::: "memory");
        }
        __builtin_amdgcn_s_barrier();
        __builtin_amdgcn_sched_barrier(0);

        bf16x8 a[2][2], b[2][2];
#pragma unroll
        for (int i = 0; i < 2; ++i) {
            const int row = wr * 32 + i * 16 + lr;
#pragma unroll
            for (int s = 0; s < 2; ++s)
                a[i][s] = *(const bf16x8*)(lA + coffA + row * 64 + (((s * 4 + lg) ^ (row & 7)) * 8));
        }
#pragma unroll
        for (int j = 0; j < 2; ++j) {
            const int row = wc * 32 + j * 16 + lr;
#pragma unroll
            for (int s = 0; s < 2; ++s)
                b[j][s] = *(const bf16x8*)(lB + coffB + row * 64 + (((s * 4 + lg) ^ (row & 7)) * 8));
        }
#pragma unroll
        for (int s = 0; s < 2; ++s)
#pragma unroll
            for (int i = 0; i < 2; ++i)
#pragma unroll
                for (int j = 0; j < 2; ++j)
                    acc[i][j] = __builtin_amdgcn_mfma_f32_16x16x32_bf16(a[i][s], b[j][s], acc[i][j], 0, 0, 0);

        asm volatile("s_waitcnt lgkmcnt(0)" ::: "memory");
        __builtin_amdgcn_s_barrier();
        __builtin_amdgcn_sched_barrier(0);
    }
#undef GSTAGE2

#pragma unroll
    for (int j = 0; j < 2; ++j) {
        const int n = n0 + wc * 32 + j * 16 + lr;
#pragma unroll
        for (int i = 0; i < 2; ++i) {
#pragma unroll
            for (int r = 0; r < 4; ++r) {
                const int m = m0 + wr * 32 + i * 16 + lg * 4 + r;
                C[(size_t)m * D_ + n] = acc[i][j][r];
            }
        }
    }
}

// ---------------------------------------------------------------------------
extern "C" void kernel_launch(void* const* d_in, const int* in_sizes, int n_in,
                              void* d_out, int out_size, void* d_ws, size_t ws_size,
                              hipStream_t stream) {
    const float* X    = (const float*)d_in[0];  // [B,S,D]
    const int*   pos  = (const int*)d_in[1];    // [S]
    const float* Wqkv = (const float*)d_in[2];  // [D,3D]
    const float* Wo   = (const float*)d_in[3];  // [D,D]
    float* out = (float*)d_out;                 // [B,S,D] fp32

    char* ws = (char*)d_ws;
    u16*    Xb  = (u16*)(ws);                        // 8 MB
    u16*    WqT = (u16*)(ws + ((size_t)8  << 20));   // 6 MB
    u16*    WoT = (u16*)(ws + ((size_t)14 << 20));   // 2 MB
    float2* tab = (float2*)(ws + ((size_t)16 << 20)); // 0.5 MB
    u16*    Qb  = (u16*)(ws + ((size_t)17 << 20));   // 8 MB
    u16*    Kb  = (u16*)(ws + ((size_t)25 << 20));   // 8 MB
    u16*    VTb = (u16*)(ws + ((size_t)33 << 20));   // 8 MB
    u16*    AOb = (u16*)(ws + ((size_t)41 << 20));   // 8 MB

    prep_all<<<3088, 256, 0, stream>>>(X, Wqkv, Wo, pos, Xb, WqT, WoT, tab);

    gemm_qkv_rope<<<dim3(32, 48), 512, 0, stream>>>(Xb, WqT, tab, Qb, Kb, VTb);
    attn_mfma<<<dim3(32, 32), 256, 0, stream>>>(Qb, Kb, VTb, AOb);
    gemm_out<<<dim3(32, 16), 512, 0, stream>>>(AOb, WoT, out);
}

// Round 24
// 102.822 us; speedup vs baseline: 1.0264x; 1.0264x over previous
//
#include <hip/hip_runtime.h>
#include <hip/hip_bf16.h>
#include <math.h>

typedef unsigned short u16;
typedef unsigned int u32;
typedef __attribute__((ext_vector_type(4))) float f32x4;
typedef __attribute__((ext_vector_type(8))) short bf16x8;

#define B_ 2
#define S_ 2048
#define D_ 1024
#define H_ 16
#define DK_ 64

// v_exp_f32: computes 2^x. Name avoids glibc __exp2f macro collision.
__device__ __forceinline__ float exp2_fast(float x) {
    return __builtin_amdgcn_exp2f(x);
}

__device__ __forceinline__ u16 f2bf(float x) {
    union { __hip_bfloat16 h; u16 u; } v;
    v.h = __float2bfloat16(x);
    return v.u;
}

// pack two f32 -> one u32 of 2 bf16 (RNE), single instruction
__device__ __forceinline__ u32 cvt_pk_bf16(float a, float b) {
    u32 r;
    asm("v_cvt_pk_bf16_f32 %0, %1, %2" : "=v"(r) : "v"(a), "v"(b));
    return r;
}

__device__ __forceinline__ void gload_lds16(const u16* g, u16* l) {
    __builtin_amdgcn_global_load_lds(
        (const __attribute__((address_space(1))) unsigned int*)g,
        (__attribute__((address_space(3))) unsigned int*)l, 16, 0, 0);
}

// ---------------------------------------------------------------------------
// Fused prep kernel: one launch, flat grid of 3088 blocks. (Passing R20/R21.)
// ---------------------------------------------------------------------------
__device__ __forceinline__ void transpose_tile_body(
    const float* __restrict__ W, u16* __restrict__ WT, int N,
    int k0, int n0, int t, float (*tile)[65])
{
    const int r = t >> 4, c4 = (t & 15) * 4;
#pragma unroll
    for (int p = 0; p < 4; ++p) {
        float4 v = *(const float4*)&W[(size_t)(k0 + r + p * 16) * N + n0 + c4];
        tile[r + p * 16][c4 + 0] = v.x;
        tile[r + p * 16][c4 + 1] = v.y;
        tile[r + p * 16][c4 + 2] = v.z;
        tile[r + p * 16][c4 + 3] = v.w;
    }
    __syncthreads();
    const int nl = t >> 2, kc = (t & 3) * 16;
    u16 buf[16];
#pragma unroll
    for (int j = 0; j < 16; ++j) buf[j] = f2bf(tile[kc + j][nl]);
    const size_t idx = (size_t)(n0 + nl) * 1024 + k0 + kc;
    u32 px[8];
#pragma unroll
    for (int j = 0; j < 8; ++j) px[j] = (u32)buf[2 * j] | ((u32)buf[2 * j + 1] << 16);
    *(uint4*)&WT[idx]     = make_uint4(px[0], px[1], px[2], px[3]);
    *(uint4*)&WT[idx + 8] = make_uint4(px[4], px[5], px[6], px[7]);
}

__global__ __launch_bounds__(256) void prep_all(
    const float* __restrict__ X, const float* __restrict__ Wqkv,
    const float* __restrict__ Wo, const int* __restrict__ pos,
    u16* __restrict__ Xb, u16* __restrict__ WqT, u16* __restrict__ WoT,
    float2* __restrict__ tab)
{
    __shared__ float tile[64][65];
    const int bid = blockIdx.x;
    const int t = threadIdx.x;

    if (bid < 2048) {
        // ---- cast X fp32 -> bf16 ----
        const int i = (bid * 256 + t) * 8;
        float4 a = *(const float4*)(X + i);
        float4 b = *(const float4*)(X + i + 4);
        u32 p0 = cvt_pk_bf16(a.x, a.y);
        u32 p1 = cvt_pk_bf16(a.z, a.w);
        u32 p2 = cvt_pk_bf16(b.x, b.y);
        u32 p3 = cvt_pk_bf16(b.z, b.w);
        *(uint4*)(Xb + i) = make_uint4(p0, p1, p2, p3);
    } else if (bid < 2816) {
        const int tl = bid - 2048;            // 0..767 = 16 k-tiles x 48 n-tiles
        transpose_tile_body(Wqkv, WqT, 3072, (tl & 15) * 64, (tl >> 4) * 64, t, tile);
    } else if (bid < 3072) {
        const int tl = bid - 2816;            // 0..255 = 16 x 16
        transpose_tile_body(Wo, WoT, 1024, (tl & 15) * 64, (tl >> 4) * 64, t, tile);
    } else {
        // ---- RoPE table: 65536 entries over 16 blocks ----
        const int base = (bid - 3072) * 256 + t;
#pragma unroll
        for (int k = 0; k < 16; ++k) {
            const int i = base + k * 4096;
            const int s = i >> 5, j = i & 31;
            const float freq = __powf(10000.f, -(float)(2 * j) * (1.f / 64.f));
            const float ang = (float)pos[s] * freq;
            float sn, cs;
            sincosf(ang, &sn, &cs);
            tab[i] = make_float2(cs, sn);
        }
    }
}

// ---------------------------------------------------------------------------
// GEMM mainloop: 128x128 tile, BK=64, 512 threads = 8 waves (4M x 2N).
// Double-buffered, counted vmcnt(4). (Unchanged from passing R11-R21 build.)
// ---------------------------------------------------------------------------
__device__ __forceinline__ void gemm_mainloop_128x64(
    const u16* __restrict__ A, const u16* __restrict__ BT, int K,
    int m0, int n0, int tid, int l, int w,
    u16* lA, u16* lB, f32x4 acc[2][4])   // lA,lB: [2][128*64] contiguous
{
    const int wr = w >> 1, wc = w & 1, lr = l & 15, lg = l >> 4;
    const int srow = tid >> 3;                     // 0..63
    const int cg   = (tid & 7) ^ (srow & 7);       // (srow+64)&7 == srow&7
    const u16* gA = A + (size_t)(m0 + srow) * K + cg * 8;
    const u16* gB = BT + (size_t)(n0 + srow) * K + cg * 8;
    const int dst0 = tid * 8;                      // lane-linear LDS dest

#define GSTAGE(k0, off)                                              \
    do {                                                             \
        gload_lds16(gA + (k0),          lA + (off) + dst0);          \
        gload_lds16(gA + (k0) + 64 * K, lA + (off) + 4096 + dst0);   \
        gload_lds16(gB + (k0),          lB + (off) + dst0);          \
        gload_lds16(gB + (k0) + 64 * K, lB + (off) + 4096 + dst0);   \
    } while (0)

    GSTAGE(0, 0);   // prologue; first iteration's vmcnt(4) waits for it

    const int NT = K >> 6;   // 16 K-tiles
    for (int t = 0; t < NT; ++t) {
        const int coff = (t & 1) * 8192;
        if (t + 1 < NT) {
            GSTAGE((t + 1) * 64, coff ^ 8192);     // prefetch: stays in flight
            asm volatile("s_waitcnt vmcnt(4)" ::: "memory");  // cur landed
        } else {
            asm volatile("s_waitcnt vmcnt(0)" ::: "memory");
        }
        __builtin_amdgcn_s_barrier();
        __builtin_amdgcn_sched_barrier(0);

        bf16x8 a[2][2], b[4][2];
#pragma unroll
        for (int i = 0; i < 2; ++i) {
            const int row = wr * 32 + i * 16 + lr;
#pragma unroll
            for (int s = 0; s < 2; ++s)
                a[i][s] = *(const bf16x8*)(lA + coff + row * 64 + (((s * 4 + lg) ^ (row & 7)) * 8));
        }
#pragma unroll
        for (int j = 0; j < 4; ++j) {
            const int row = wc * 64 + j * 16 + lr;
#pragma unroll
            for (int s = 0; s < 2; ++s)
                b[j][s] = *(const bf16x8*)(lB + coff + row * 64 + (((s * 4 + lg) ^ (row & 7)) * 8));
        }
#pragma unroll
        for (int s = 0; s < 2; ++s)
#pragma unroll
            for (int i = 0; i < 2; ++i)
#pragma unroll
                for (int j = 0; j < 4; ++j)
                    acc[i][j] = __builtin_amdgcn_mfma_f32_16x16x32_bf16(a[i][s], b[j][s], acc[i][j], 0, 0, 0);

        asm volatile("s_waitcnt lgkmcnt(0)" ::: "memory");  // reads done
        __builtin_amdgcn_s_barrier();              // next overwrite safe
        __builtin_amdgcn_sched_barrier(0);
    }
#undef GSTAGE
}

// ---------------------------------------------------------------------------
// Kernel: QKV GEMM + RoPE epilogue (R21 passing build: 128x128 tiles).
// Q scaled by 0.125*log2(e). Q,K roped -> [B,H,S,DK]; V -> [B,H,DK,S] (V^T).
// ---------------------------------------------------------------------------
__global__ __launch_bounds__(512, 4) void gemm_qkv_rope(
    const u16* __restrict__ A, const u16* __restrict__ BT,
    const float2* __restrict__ tab,
    u16* __restrict__ qo, u16* __restrict__ ko, u16* __restrict__ vto)
{
    __shared__ u16 lA[2 * 128 * 64];
    __shared__ u16 lB[2 * 128 * 64];
    const int tid = threadIdx.x, l = tid & 63, w = tid >> 6;
    const int m0 = blockIdx.x * 128, n0 = blockIdx.y * 128;

    f32x4 acc[2][4] = {};
    gemm_mainloop_128x64(A, BT, 1024, m0, n0, tid, l, w, lA, lB, acc);

    const int wr = w >> 1, wc = w & 1, lr = l & 15, lg = l >> 4;
    const int region = n0 >> 10;  // 0=Q,1=K,2=V (tile never crosses regions)

    if (region < 2) {
        u16* dst = (region == 0) ? qo : ko;
        const float qscale = (region == 0) ? (0.125f * 1.44269504088896f) : 1.0f;
#pragma unroll
        for (int j = 0; j < 4; ++j) {
            const int nb = n0 + wc * 64 + j * 16;
            const int h = (nb >> 6) & 15;
            const int c = j * 16 + lr;          // col within head (0..63)
#pragma unroll
            for (int i = 0; i < 2; ++i) {
#pragma unroll
                for (int r = 0; r < 4; ++r) {
                    const int m = m0 + wr * 32 + i * 16 + lg * 4 + r;
                    const int bb = m >> 11, s = m & (S_ - 1);
                    const float2 cs = tab[s * 32 + (c >> 1)];
                    const float v = acc[i][j][r];
                    const float vp = __shfl_xor(v, 1);
                    float outv = ((lr & 1) == 0) ? (v * cs.x - vp * cs.y)
                                                 : (v * cs.x + vp * cs.y);
                    outv *= qscale;
                    dst[(((size_t)bb * H_ + h) * S_ + s) * DK_ + c] = f2bf(outv);
                }
            }
        }
    } else {
#pragma unroll
        for (int j = 0; j < 4; ++j) {
            const int nb = n0 + wc * 64 + j * 16;
            const int h = (nb >> 6) & 15;
            const int c = j * 16 + lr;
#pragma unroll
            for (int i = 0; i < 2; ++i) {
                // 4 r-values -> 4 consecutive s (same bb; base 4-aligned,
                // never crosses the 2048 boundary). Pack into one uint2.
                const int m = m0 + wr * 32 + i * 16 + lg * 4;
                const int bb = m >> 11, s = m & (S_ - 1);
                const u32 lo = cvt_pk_bf16(acc[i][j][0], acc[i][j][1]);
                const u32 hi = cvt_pk_bf16(acc[i][j][2], acc[i][j][3]);
                *(uint2*)&vto[(((size_t)bb * H_ + h) * DK_ + c) * S_ + s] =
                    make_uint2(lo, hi);
            }
        }
    }
}

// ---------------------------------------------------------------------------
// Flash attention (R16, passing): KVBLK=128, double-buffered LDS,
// XCD-local grid, swapped-operand MFMA, no-max exp2 softmax + MFMA
// ones-trick row-sum. UNCHANGED from the R16/R19/R20/R21 passing build.
// ---------------------------------------------------------------------------
__global__ __launch_bounds__(256) void attn_mfma(
    const u16* __restrict__ Qg, const u16* __restrict__ Kg,
    const u16* __restrict__ VTg, u16* __restrict__ Og)
{
    __shared__ u16 sK[2][128 * 64];    // [key][d]
    __shared__ u16 sV[2][64 * 128];    // [d][key]
    const int t = threadIdx.x, l = t & 63, w = t >> 6;
    const int lr = l & 15, lg = l >> 4;
    const int bh = blockIdx.x;          // id%8 == bh%8 -> XCD-local K/V
    const int qt = 31 - blockIdx.y;     // LPT: longest stripes first
    const int q0 = qt * 64 + w * 16;
    const int dt = qt >> 1;             // diagonal 128-key tile
    const int NT = dt + 1;
    const int qloc = (qt & 1) * 64 + w * 16 + lr;  // causal bound in dt

    const u16* Kbh = Kg + (size_t)bh * S_ * DK_;
    const u16* Vbh = VTg + (size_t)bh * DK_ * S_;

    const u16* Qp = Qg + ((size_t)bh * S_ + q0) * DK_;
    bf16x8 qa[2];
    qa[0] = *(const bf16x8*)(Qp + lr * DK_ + lg * 8);
    qa[1] = *(const bf16x8*)(Qp + lr * DK_ + 32 + lg * 8);

    // all-ones bf16 fragment for the MFMA row-sum (bf16 1.0 = 0x3F80)
    union { u32 wd[4]; bf16x8 v; } ones;
#pragma unroll
    for (int i = 0; i < 4; ++i) ones.wd[i] = 0x3F803F80u;

    // staging: K wave rows w*32..+31 (4 issues x 8 rows, 128B rows);
    //          V wave d-rows w*16..+15 (4 issues x 4 rows, 256B rows)
    const int kcg = (l & 7) ^ (l >> 3);   // krow&7 == l>>3 (w*32, i*8 = 0 mod 8)

#define STAGE(kt, b)                                                          \
    do {                                                                      \
        _Pragma("unroll")                                                     \
        for (int i = 0; i < 4; ++i) {                                         \
            const int kr = w * 32 + i * 8 + (l >> 3);                         \
            gload_lds16(Kbh + ((size_t)(kt) * 128 + kr) * DK_ + kcg * 8,      \
                        &sK[b][(w * 32 + i * 8) * 64]);                       \
        }                                                                     \
        _Pragma("unroll")                                                     \
        for (int i = 0; i < 4; ++i) {                                         \
            const int vr = w * 16 + i * 4 + (l >> 4);                         \
            const int vc = (l & 15) ^ ((i * 4 + (l >> 4)) & 15);              \
            gload_lds16(Vbh + (size_t)vr * S_ + (kt) * 128 + vc * 8,          \
                        &sV[b][(w * 16 + i * 4) * 128]);                      \
        }                                                                     \
    } while (0)

    f32x4 o[4] = {};                    // O^T: o[jf][r] = O[d][q=lr]
    f32x4 o5 = {};                      // row-sum accumulator (all rows equal)

    const int s0 = lr + 32 * (lg & 1);  // P-redistribution source lanes
    const int s1 = s0 + 16;
    const bool hi2 = (lg >= 2);

    STAGE(0, 0);
    asm volatile("s_waitcnt vmcnt(0)" ::: "memory");
    __syncthreads();

    for (int kt = 0; kt < NT; ++kt) {
        const int cur = kt & 1;
        if (kt + 1 < NT) STAGE(kt + 1, cur ^ 1);

        // ---- QK^T swapped: s4[kf] = K_frag x Q_frag -> [key][q], kf 0..7 ----
        f32x4 s4[8] = {};
        __builtin_amdgcn_s_setprio(1);
#pragma unroll
        for (int kf = 0; kf < 8; ++kf) {
            const int row = kf * 16 + lr;
#pragma unroll
            for (int ks = 0; ks < 2; ++ks) {
                bf16x8 kb = *(const bf16x8*)(&sK[cur][row * 64 + (((ks * 4 + lg) ^ (row & 7)) * 8)]);
                s4[kf] = __builtin_amdgcn_mfma_f32_16x16x32_bf16(kb, qa[ks], s4[kf], 0, 0, 0);
            }
        }
        __builtin_amdgcn_s_setprio(0);
        if (kt == dt) {
#pragma unroll
            for (int kf = 0; kf < 8; ++kf)
#pragma unroll
                for (int r = 0; r < 4; ++r)
                    if (kf * 16 + lg * 4 + r > qloc) s4[kf][r] = -3.0e38f;
        }

        // ---- no-max softmax: P = exp2(S) (masked -> 0); no reductions ----
#pragma unroll
        for (int kf = 0; kf < 8; ++kf)
#pragma unroll
            for (int r = 0; r < 4; ++r)
                s4[kf][r] = exp2_fast(s4[kf][r]);

        // ---- P redistribution (regs only): pk[8][2] -> pa[4] ----
        u32 pk[8][2];
#pragma unroll
        for (int kf = 0; kf < 8; ++kf) {
            pk[kf][0] = cvt_pk_bf16(s4[kf][0], s4[kf][1]);
            pk[kf][1] = cvt_pk_bf16(s4[kf][2], s4[kf][3]);
        }
        union { u32 wd[4]; bf16x8 v; } pa[4];
#pragma unroll
        for (int ks = 0; ks < 4; ++ks) {
            const u32 lo0 = pk[2 * ks][0],     lo1 = pk[2 * ks][1];
            const u32 hi0 = pk[2 * ks + 1][0], hi1 = pk[2 * ks + 1][1];
            const u32 a0 = __shfl(lo0, s0), b0 = __shfl(hi0, s0);
            const u32 a1 = __shfl(lo1, s0), b1 = __shfl(hi1, s0);
            const u32 a2 = __shfl(lo0, s1), b2 = __shfl(hi0, s1);
            const u32 a3 = __shfl(lo1, s1), b3 = __shfl(hi1, s1);
            pa[ks].wd[0] = hi2 ? b0 : a0;
            pa[ks].wd[1] = hi2 ? b1 : a1;
            pa[ks].wd[2] = hi2 ? b2 : a2;
            pa[ks].wd[3] = hi2 ? b3 : a3;
        }

        // ---- PV swapped + MFMA row-sum: o += V x P ; o5 += ones x P ----
        __builtin_amdgcn_s_setprio(1);
#pragma unroll
        for (int ks = 0; ks < 4; ++ks) {
#pragma unroll
            for (int jf = 0; jf < 4; ++jf) {
                const int row = jf * 16 + lr;
                bf16x8 vb = *(const bf16x8*)(&sV[cur][row * 128 + (((ks * 4 + lg) ^ (row & 15)) * 8)]);
                o[jf] = __builtin_amdgcn_mfma_f32_16x16x32_bf16(vb, pa[ks].v, o[jf], 0, 0, 0);
            }
            o5 = __builtin_amdgcn_mfma_f32_16x16x32_bf16(ones.v, pa[ks].v, o5, 0, 0, 0);
        }
        __builtin_amdgcn_s_setprio(0);

        asm volatile("s_waitcnt vmcnt(0)" ::: "memory");
        __syncthreads();
    }
#undef STAGE

    // ---- epilogue: normalize by li = o5[0], write O^T to [B,S,D] bf16 ----
    const float inv = 1.f / o5[0];
    const int b = bh >> 4, h = bh & 15;
    const int srow = q0 + lr;
    u16* orow = Og + ((size_t)b * S_ + srow) * D_ + h * DK_;
#pragma unroll
    for (int jf = 0; jf < 4; ++jf) {
#pragma unroll
        for (int p = 0; p < 2; ++p) {
            const u32 wv = cvt_pk_bf16(o[jf][2 * p] * inv, o[jf][2 * p + 1] * inv);
            *(u32*)(orow + jf * 16 + lg * 4 + 2 * p) = wv;
        }
    }
}

// ---------------------------------------------------------------------------
// Kernel: out = attn[4096][1024] @ Wo, fp32 out. 128x64 tiles, grid (32,16)
// = 512 blocks = 2 blocks/CU. (Passing R21 build, unchanged.)
// ---------------------------------------------------------------------------
__global__ __launch_bounds__(512, 4) void gemm_out(
    const u16* __restrict__ A, const u16* __restrict__ BT, float* __restrict__ C)
{
    __shared__ u16 lA[2 * 128 * 64];
    __shared__ u16 lB[2 * 64 * 64];
    const int tid = threadIdx.x, l = tid & 63, w = tid >> 6;
    const int m0 = blockIdx.x * 128, n0 = blockIdx.y * 64;
    const int K = 1024;

    const int wr = w >> 1, wc = w & 1, lr = l & 15, lg = l >> 4;
    const int srow = tid >> 3;                     // 0..63
    const int cg   = (tid & 7) ^ (srow & 7);
    const u16* gA = A + (size_t)(m0 + srow) * K + cg * 8;
    const u16* gB = BT + (size_t)(n0 + srow) * K + cg * 8;
    const int dst0 = tid * 8;

    f32x4 acc[2][2] = {};

#define GSTAGE2(k0, offA, offB)                                      \
    do {                                                             \
        gload_lds16(gA + (k0),          lA + (offA) + dst0);         \
        gload_lds16(gA + (k0) + 64 * K, lA + (offA) + 4096 + dst0);  \
        gload_lds16(gB + (k0),          lB + (offB) + dst0);         \
    } while (0)

    GSTAGE2(0, 0, 0);

    const int NT = K >> 6;   // 16 K-tiles
    for (int t = 0; t < NT; ++t) {
        const int coffA = (t & 1) * 8192;
        const int coffB = (t & 1) * 4096;
        if (t + 1 < NT) {
            GSTAGE2((t + 1) * 64, coffA ^ 8192, coffB ^ 4096);
            asm volatile("s_waitcnt vmcnt(3)" ::: "memory");  // cur landed
        } else {
            asm volatile("s_waitcnt vmcnt(0)" ::: "memory");
        }
        __builtin_amdgcn_s_barrier();
        __builtin_amdgcn_sched_barrier(0);

        bf16x8 a[2][2], b[2][2];
#pragma unroll
        for (int i = 0; i < 2; ++i) {
            const int row = wr * 32 + i * 16 + lr;
#pragma unroll
            for (int s = 0; s < 2; ++s)
                a[i][s] = *(const bf16x8*)(lA + coffA + row * 64 + (((s * 4 + lg) ^ (row & 7)) * 8));
        }
#pragma unroll
        for (int j = 0; j < 2; ++j) {
            const int row = wc * 32 + j * 16 + lr;
#pragma unroll
            for (int s = 0; s < 2; ++s)
                b[j][s] = *(const bf16x8*)(lB + coffB + row * 64 + (((s * 4 + lg) ^ (row & 7)) * 8));
        }
#pragma unroll
        for (int s = 0; s < 2; ++s)
#pragma unroll
            for (int i = 0; i < 2; ++i)
#pragma unroll
                for (int j = 0; j < 2; ++j)
                    acc[i][j] = __builtin_amdgcn_mfma_f32_16x16x32_bf16(a[i][s], b[j][s], acc[i][j], 0, 0, 0);

        asm volatile("s_waitcnt lgkmcnt(0)" ::: "memory");
        __builtin_amdgcn_s_barrier();
        __builtin_amdgcn_sched_barrier(0);
    }
#undef GSTAGE2

#pragma unroll
    for (int j = 0; j < 2; ++j) {
        const int n = n0 + wc * 32 + j * 16 + lr;
#pragma unroll
        for (int i = 0; i < 2; ++i) {
#pragma unroll
            for (int r = 0; r < 4; ++r) {
                const int m = m0 + wr * 32 + i * 16 + lg * 4 + r;
                C[(size_t)m * D_ + n] = acc[i][j][r];
            }
        }
    }
}

// ---------------------------------------------------------------------------
extern "C" void kernel_launch(void* const* d_in, const int* in_sizes, int n_in,
                              void* d_out, int out_size, void* d_ws, size_t ws_size,
                              hipStream_t stream) {
    const float* X    = (const float*)d_in[0];  // [B,S,D]
    const int*   pos  = (const int*)d_in[1];    // [S]
    const float* Wqkv = (const float*)d_in[2];  // [D,3D]
    const float* Wo   = (const float*)d_in[3];  // [D,D]
    float* out = (float*)d_out;                 // [B,S,D] fp32

    char* ws = (char*)d_ws;
    u16*    Xb  = (u16*)(ws);                        // 8 MB
    u16*    WqT = (u16*)(ws + ((size_t)8  << 20));   // 6 MB
    u16*    WoT = (u16*)(ws + ((size_t)14 << 20));   // 2 MB
    float2* tab = (float2*)(ws + ((size_t)16 << 20)); // 0.5 MB
    u16*    Qb  = (u16*)(ws + ((size_t)17 << 20));   // 8 MB
    u16*    Kb  = (u16*)(ws + ((size_t)25 << 20));   // 8 MB
    u16*    VTb = (u16*)(ws + ((size_t)33 << 20));   // 8 MB
    u16*    AOb = (u16*)(ws + ((size_t)41 << 20));   // 8 MB

    prep_all<<<3088, 256, 0, stream>>>(X, Wqkv, Wo, pos, Xb, WqT, WoT, tab);

    gemm_qkv_rope<<<dim3(32, 24), 512, 0, stream>>>(Xb, WqT, tab, Qb, Kb, VTb);
    attn_mfma<<<dim3(32, 32), 256, 0, stream>>>(Qb, Kb, VTb, AOb);
    gemm_out<<<dim3(32, 16), 512, 0, stream>>>(AOb, WoT, out);
}